// Round 10
// baseline (122.368 us; speedup 1.0000x reference)
//
#include <hip/hip_runtime.h>

// Per-element MLP 1->32->(32x32)x9->1, leaky relu, v_mfma_f32_16x16x32_f16.
// R10: R9 showed the compiler re-reads LDS-staged weights per layer instead of
// keeping them resident (VGPR dropped to 84 < the 120 needed). Fixes:
//  (1) LDS-staged cooperative weight load (preamble ~1us, not 15us of gathers)
//      then ds_read_b128 -> regs + asm memory clobber => compiler MUST keep
//      the 72 weight VGPRs resident (can't prove LDS unchanged afterwards).
//  (2) bias moved into the MFMA C operand (f32 from LDS, rolling 1-layer
//      prefetch, same-address broadcast within each 16-lane group) => the
//      pk_add disappears from the per-element epilogue (-20% VALU floor).
//  (3) plain __launch_bounds__(256): R7 proved min-waves forcing spills.
// Grid 512 = 2 blocks/CU known-good residency.
#define NLAYERS 9
#define HID 32
#define SLOPE 0.01f
#define NCHAIN 8

typedef _Float16 v2h __attribute__((ext_vector_type(2)));
typedef _Float16 v8h __attribute__((ext_vector_type(8)));
typedef float v4f __attribute__((ext_vector_type(4)));

union U8 { v8h v; v2h p[4]; };   // B operand: 8 f16 = 4 VGPRs

__device__ __forceinline__ v2h pk_cvt(float a, float b) {
    return __builtin_bit_cast(v2h, __builtin_amdgcn_cvt_pkrtz(a, b));
}
__device__ __forceinline__ v2h leaky2(v2h t, v2h s) {
    return __builtin_elementwise_max(t, t * s);
}

__global__ __launch_bounds__(256) void mlp_mfma_kernel(
    const float* __restrict__ x,
    const float* __restrict__ W_in,   // [1,32]
    const float* __restrict__ b_in,   // [32]
    const float* __restrict__ W_hid,  // [9,32,32]  W[l][k_in][n_out]
    const float* __restrict__ b_hid,  // [9,32]
    const float* __restrict__ W_out,  // [32,1]
    const float* __restrict__ b_out,  // [1]
    float* __restrict__ out, int N)
{
    // Weight fragments: [l][a][g][c][j]; lane (g,c), half a, layer l holds
    // W[8g+j][8*(c>>2)+4a+(c&3)], j=0..7 (16B -> one ds_read_b128).
    __shared__ __align__(16) _Float16 wfrag[NLAYERS][2][4][16][8];  // 18 KB
    // f32 bias as MFMA C operand: [l][a][g][r] = b_hid[l][8g+4a+r]
    __shared__ __align__(16) float biasC[NLAYERS][2][4][4];         // 1.1 KB

    // cooperative coalesced read of W_hid (9216 f32), scatter-convert to LDS
    for (int t = threadIdx.x; t < NLAYERS * HID * HID; t += blockDim.x) {
        int l = t >> 10;            // / (32*32)
        int rem = t & 1023;
        int k = rem >> 5, n = rem & 31;
        int a = (n >> 2) & 1;
        int g = k >> 3, j = k & 7;
        int c = ((n >> 3) << 2) | (n & 3);
        wfrag[l][a][g][c][j] = (_Float16)W_hid[t];
    }
    for (int t = threadIdx.x; t < NLAYERS * HID; t += blockDim.x) {
        int l = t >> 5, u = t & 31;
        int g = u >> 3, a = (u >> 2) & 1, r = u & 3;   // u = 8g+4a+r
        biasC[l][a][g][r] = b_hid[t];
    }
    __syncthreads();

    const int lane = threadIdx.x & 63;
    const int g    = lane >> 4;    // k-group (A/B), row-group (C)
    const int c    = lane & 15;    // batch col; also A output-row

    // ---- weight fragments into registers (18 conflict-free ds_read_b128) ----
    v8h aW[NLAYERS][2];
#pragma unroll
    for (int l = 0; l < NLAYERS; ++l)
#pragma unroll
        for (int a = 0; a < 2; ++a)
            aW[l][a] = *(const v8h*)&wfrag[l][a][g][c][0];
    // Force residency: after this, the compiler may not assume LDS is
    // unchanged, so it cannot legally re-read wfrag instead of keeping aW.
    asm volatile("" ::: "memory");

    // per-lane unit slice 8g..8g+7 of in/out layer params, packed pairs
    v2h win2[4], bin2[4], wout2[4];
#pragma unroll
    for (int u = 0; u < 4; ++u) {
        int d = 8 * g + 2 * u;
        win2[u]  = v2h{(_Float16)W_in[d],  (_Float16)W_in[d + 1]};
        bin2[u]  = v2h{(_Float16)b_in[d],  (_Float16)b_in[d + 1]};
        wout2[u] = v2h{(_Float16)W_out[d], (_Float16)W_out[d + 1]};
    }
    const float bo = b_out[0];
    const v2h slope2 = v2h{(_Float16)SLOPE, (_Float16)SLOPE};

    const int nwaves = (gridDim.x * blockDim.x) >> 6;
    const int wid    = (blockIdx.x * blockDim.x + threadIdx.x) >> 6;
    const int niter  = (N + NCHAIN * 16 - 1) / (NCHAIN * 16);

    // ---- x prefetch for first iteration ----
    float xc[NCHAIN];
#pragma unroll
    for (int ch = 0; ch < NCHAIN; ++ch) {
        int idx = wid * (NCHAIN * 16) + ch * 16 + c;
        xc[ch] = (wid < niter && idx < N) ? x[idx] : 0.0f;
    }

    for (int it = wid; it < niter; it += nwaves) {
        // prefetch next iteration's x
        float xn[NCHAIN];
        {
            int nit = it + nwaves;
#pragma unroll
            for (int ch = 0; ch < NCHAIN; ++ch) {
                int idx = nit * (NCHAIN * 16) + ch * 16 + c;
                xn[ch] = (nit < niter && idx < N) ? x[idx] : 0.0f;
            }
        }

        // ---- input layer ----
        U8 hb[NCHAIN];
#pragma unroll
        for (int ch = 0; ch < NCHAIN; ++ch) {
            _Float16 xh = (_Float16)xc[ch];
            v2h x2 = v2h{xh, xh};
#pragma unroll
            for (int u = 0; u < 4; ++u)
                hb[ch].p[u] = leaky2(x2 * win2[u] + bin2[u], slope2);
        }

        // ---- 9 hidden layers; bias rides in the MFMA C operand ----
        v4f bc0 = *(const v4f*)&biasC[0][0][g][0];
        v4f bc1 = *(const v4f*)&biasC[0][1][g][0];
#pragma unroll
        for (int l = 0; l < NLAYERS; ++l) {
            // rolling prefetch of next layer's bias (hides ds_read latency)
            v4f nb0 = bc0, nb1 = bc1;
            if (l + 1 < NLAYERS) {
                nb0 = *(const v4f*)&biasC[l + 1][0][g][0];
                nb1 = *(const v4f*)&biasC[l + 1][1][g][0];
            }

            v4f a0[NCHAIN], a1[NCHAIN];
            // all 16 MFMAs are mutually independent; C = bias (free add)
#pragma unroll
            for (int ch = 0; ch < NCHAIN; ++ch) {
                a0[ch] = __builtin_amdgcn_mfma_f32_16x16x32_f16(aW[l][0], hb[ch].v, bc0, 0, 0, 0);
                a1[ch] = __builtin_amdgcn_mfma_f32_16x16x32_f16(aW[l][1], hb[ch].v, bc1, 0, 0, 0);
            }
#pragma unroll
            for (int ch = 0; ch < NCHAIN; ++ch) {
                hb[ch].p[0] = leaky2(pk_cvt(a0[ch][0], a0[ch][1]), slope2);
                hb[ch].p[1] = leaky2(pk_cvt(a0[ch][2], a0[ch][3]), slope2);
                hb[ch].p[2] = leaky2(pk_cvt(a1[ch][0], a1[ch][1]), slope2);
                hb[ch].p[3] = leaky2(pk_cvt(a1[ch][2], a1[ch][3]), slope2);
            }
            bc0 = nb0; bc1 = nb1;
        }

        // ---- output layer: lane covers units 8g..8g+7; reduce over groups ----
#pragma unroll
        for (int ch = 0; ch < NCHAIN; ++ch) {
            float p = 0.0f;
#pragma unroll
            for (int u = 0; u < 4; ++u) {
                p = fmaf((float)hb[ch].p[u][0], (float)wout2[u][0], p);
                p = fmaf((float)hb[ch].p[u][1], (float)wout2[u][1], p);
            }
            p += __shfl_xor(p, 16, 64);
            p += __shfl_xor(p, 32, 64);
            float o = p + bo;
            int idx = it * (NCHAIN * 16) + ch * 16 + c;
            // spread the 8 chains' stores across the 4 lane-groups
            if (g == (ch & 3) && idx < N) out[idx] = o;
        }

#pragma unroll
        for (int ch = 0; ch < NCHAIN; ++ch) xc[ch] = xn[ch];
    }
}

extern "C" void kernel_launch(void* const* d_in, const int* in_sizes, int n_in,
                              void* d_out, int out_size, void* d_ws, size_t ws_size,
                              hipStream_t stream) {
    const float* x     = (const float*)d_in[0];
    const float* W_in  = (const float*)d_in[1];
    const float* b_in  = (const float*)d_in[2];
    const float* W_hid = (const float*)d_in[3];
    const float* b_hid = (const float*)d_in[4];
    const float* W_out = (const float*)d_in[5];
    const float* b_out = (const float*)d_in[6];
    float* out = (float*)d_out;

    int N = in_sizes[0];
    // 512 blocks x 4 waves = 2048 waves = 2 blocks/CU; 8192 iterations of
    // 128 batch -> exactly 4 per wave; weights VGPR-resident via clobber.
    dim3 block(256);
    dim3 grid(512);
    mlp_mfma_kernel<<<grid, block, 0, stream>>>(x, W_in, b_in, W_hid, b_hid,
                                                W_out, b_out, out, N);
}